// Round 6
// baseline (253.805 us; speedup 1.0000x reference)
//
#include <hip/hip_runtime.h>
#include <math.h>

#define NE 8
#define KDIM 4096
#define PDIM 64
#define NQ 2                  // K split: halves
#define QK (KDIM / NQ)        // 2048 floats per half
#define LROW (QK + 16)        // padded LDS row stride (floats)
#define EPS_F32 1.1920929e-07f

typedef float f4 __attribute__((ext_vector_type(4)));

// Phase 1: partial logits.
// Block = 512 threads = 8 waves, covers 32 tokens x K-half q. Grid = 512 blocks
// -> 2 blocks/CU, 16 waves/CU, ENTIRE grid co-resident (one generation).
// W half staged transposed into LDS once per block (verified R5 pattern).
// Each wave: 4 tokens, 8 chunk-steps, rolling depth-2 register prefetch of
// NT x loads -> continuous issue stream, ~8KB in flight per wave steady.
__global__ __launch_bounds__(512, 4)   // 4 waves/EU -> 2 blocks/CU, VGPR<=128
void gate_partial(const float* __restrict__ x,
                  const float* __restrict__ prompt,
                  const float* __restrict__ W,
                  float* __restrict__ partials,   // [NQ][tokens][NE]
                  int tokens)
{
    const int tid   = threadIdx.x;
    const int lane  = tid & 63;
    const int wave  = tid >> 6;          // 0..7
    const int group = blockIdx.x >> 1;
    const int q     = blockIdx.x & 1;
    const int tbase = group * 32 + wave * 4;
    const int k0    = q * QK;

    __shared__ float lds_w[NE][LROW];    // 66,048 B
    __shared__ float lds_wp[NE][68];     // prompt W, 2,176 B (q==1 only)

    // ---- stage W half transposed into LDS: rows [k0,k0+QK) x 8 = 4096 f4 ----
    const float* Wq = W + (size_t)k0 * NE;
#pragma unroll
    for (int it = 0; it < 8; ++it) {
        const int m  = it * 512 + tid;   // f4 index 0..4095
        const f4 v   = *(const f4*)(Wq + 4 * m);
        const int kl = m >> 1;
        const int e0 = (m & 1) * 4;
        lds_w[e0 + 0][kl] = v.x;         // 2-way bank alias: free
        lds_w[e0 + 1][kl] = v.y;
        lds_w[e0 + 2][kl] = v.z;
        lds_w[e0 + 3][kl] = v.w;
    }
    // prompt W rows 4096..4159 x 8 = 128 f4 (q==1 blocks)
    if (q == 1 && tid < 128) {
        const f4 v   = *(const f4*)(W + (size_t)KDIM * NE + 4 * tid);
        const int kl = tid >> 1;
        const int e0 = (tid & 1) * 4;
        lds_wp[e0 + 0][kl] = v.x;
        lds_wp[e0 + 1][kl] = v.y;
        lds_wp[e0 + 2][kl] = v.z;
        lds_wp[e0 + 3][kl] = v.w;
    }

    // ---- prime x prefetch (steps 0,1) before the barrier ----
    const float* xw = x + (size_t)tbase * KDIM + k0 + lane * 4;
    f4 xv[2][4];
#pragma unroll
    for (int s = 0; s < 2; ++s)
#pragma unroll
        for (int t = 0; t < 4; ++t)
            xv[s][t] = __builtin_nontemporal_load(
                (const f4*)(xw + (size_t)t * KDIM + s * 256));

    __syncthreads();

    float acc[4][NE];
#pragma unroll
    for (int t = 0; t < 4; ++t)
#pragma unroll
        for (int e = 0; e < NE; ++e) acc[t][e] = 0.f;

    // ---- main loop: 8 chunk-steps, rolling prefetch distance 2 ----
#pragma unroll
    for (int s = 0; s < 8; ++s) {
        const int cur = s & 1;
        const int kl  = s * 256 + lane * 4;
        // expert halves to cap register pressure
#pragma unroll
        for (int eh = 0; eh < 2; ++eh) {
            f4 wv[4];
#pragma unroll
            for (int j = 0; j < 4; ++j)
                wv[j] = *(const f4*)(&lds_w[eh * 4 + j][kl]);   // conflict-free b128
#pragma unroll
            for (int t = 0; t < 4; ++t)
#pragma unroll
                for (int j = 0; j < 4; ++j) {
                    const int e = eh * 4 + j;
                    acc[t][e] = fmaf(xv[cur][t].x, wv[j].x, acc[t][e]);
                    acc[t][e] = fmaf(xv[cur][t].y, wv[j].y, acc[t][e]);
                    acc[t][e] = fmaf(xv[cur][t].z, wv[j].z, acc[t][e]);
                    acc[t][e] = fmaf(xv[cur][t].w, wv[j].w, acc[t][e]);
                }
        }
        if (s + 2 < 8) {
#pragma unroll
            for (int t = 0; t < 4; ++t)
                xv[cur][t] = __builtin_nontemporal_load(
                    (const f4*)(xw + (size_t)t * KDIM + (s + 2) * 256));
        }
    }

    // ---- prompt (64 dims) folded into half 1 ----
    if (q == 1 && lane < 16) {
        const int k = lane * 4;
        f4 pv[4];
#pragma unroll
        for (int t = 0; t < 4; ++t)
            pv[t] = *(const f4*)(prompt + (size_t)(tbase + t) * PDIM + k);
#pragma unroll
        for (int eh = 0; eh < 2; ++eh) {
            f4 wv[4];
#pragma unroll
            for (int j = 0; j < 4; ++j)
                wv[j] = *(const f4*)(&lds_wp[eh * 4 + j][k]);
#pragma unroll
            for (int t = 0; t < 4; ++t)
#pragma unroll
                for (int j = 0; j < 4; ++j) {
                    const int e = eh * 4 + j;
                    acc[t][e] = fmaf(pv[t].x, wv[j].x, acc[t][e]);
                    acc[t][e] = fmaf(pv[t].y, wv[j].y, acc[t][e]);
                    acc[t][e] = fmaf(pv[t].z, wv[j].z, acc[t][e]);
                    acc[t][e] = fmaf(pv[t].w, wv[j].w, acc[t][e]);
                }
        }
    }

    // ---- butterfly reduce across the wave ----
#pragma unroll
    for (int t = 0; t < 4; ++t)
#pragma unroll
        for (int e = 0; e < NE; ++e) {
            float v = acc[t][e];
#pragma unroll
            for (int off = 32; off >= 1; off >>= 1)
                v += __shfl_xor(v, off, 64);
            acc[t][e] = v;
        }

    // lanes 0..31 write this wave's 4x8 partials, coalesced
    if (lane < 32) {
        const int t4 = lane >> 3;
        const int e  = lane & 7;
        partials[((size_t)q * tokens + tbase + t4) * NE + e] = acc[t4][e];
    }
}

// Phase 2: combine halves + bias, top-2, softmax, write masks & gates.
// Verified lane mapping: lane = tt*16 + kk*8 + ee -> one mask element each.
__global__ __launch_bounds__(256)
void gate_epilogue(const float* __restrict__ partials,
                   const float* __restrict__ b,
                   float* __restrict__ out,
                   int tokens)
{
    const int tid   = threadIdx.x;
    const int lane  = tid & 63;
    const int wave  = tid >> 6;
    const int tbase = blockIdx.x * 16 + wave * 4;

    const int tt = lane >> 4;
    const int kk = (lane >> 3) & 1;
    const int ee = lane & 7;
    const int tg = tbase + tt;

    float lg[NE];
#pragma unroll
    for (int e = 0; e < NE; ++e) lg[e] = b[e];
#pragma unroll
    for (int qq = 0; qq < NQ; ++qq) {
        const f4 lo = *(const f4*)(partials + ((size_t)qq * tokens + tg) * NE);
        const f4 hi = *(const f4*)(partials + ((size_t)qq * tokens + tg) * NE + 4);
        lg[0] += lo.x; lg[1] += lo.y; lg[2] += lo.z; lg[3] += lo.w;
        lg[4] += hi.x; lg[5] += hi.y; lg[6] += hi.z; lg[7] += hi.w;
    }

    // top-2, strict > so smallest index wins ties (jax.lax.top_k semantics)
    float v0 = lg[0]; int i0 = 0;
#pragma unroll
    for (int e = 1; e < NE; ++e)
        if (lg[e] > v0) { v0 = lg[e]; i0 = e; }
    float v1 = (i0 == 0) ? lg[1] : lg[0];
    int   i1 = (i0 == 0) ? 1 : 0;
#pragma unroll
    for (int e = 0; e < NE; ++e)
        if (e != i0 && lg[e] > v1) { v1 = lg[e]; i1 = e; }

    float s = 0.f;
#pragma unroll
    for (int e = 0; e < NE; ++e) s += __expf(lg[e] - v0);
    const float g0 = 1.0f / s;
    const float g1 = __expf(v1 - v0) / s;
    const float denom = fmaxf(g0 + g1, EPS_F32);

    const int sel = kk ? i1 : i0;
    out[(size_t)tg * 16 + kk * 8 + ee] = (ee == sel) ? 1.0f : 0.0f;

    if ((lane & 15) < 2) {
        const float g = (ee == 0) ? (g0 / denom) : (g1 / denom);
        out[(size_t)tokens * 16 + (size_t)tg * 2 + ee] = g;
    }
}

extern "C" void kernel_launch(void* const* d_in, const int* in_sizes, int n_in,
                              void* d_out, int out_size, void* d_ws, size_t ws_size,
                              hipStream_t stream) {
    const float* x      = (const float*)d_in[0];
    const float* prompt = (const float*)d_in[1];
    const float* W      = (const float*)d_in[2];
    const float* b      = (const float*)d_in[3];
    float* out          = (float*)d_out;
    float* partials     = (float*)d_ws;           // NQ*tokens*NE*4 = 512 KB

    const int tokens = in_sizes[0] / KDIM;        // 8192

    hipLaunchKernelGGL(gate_partial, dim3((tokens / 32) * NQ), dim3(512), 0, stream,
                       x, prompt, W, partials, tokens);
    hipLaunchKernelGGL(gate_epilogue, dim3(tokens / 16), dim3(256), 0, stream,
                       partials, b, out, tokens);
}

// Round 7
// 206.230 us; speedup vs baseline: 1.2307x; 1.2307x over previous
//
#include <hip/hip_runtime.h>
#include <math.h>

#define NE 8
#define KDIM 4096
#define PDIM 64
#define WROWS (KDIM + PDIM)   // 4160
#define EPS_F32 1.1920929e-07f
#define NCHUNK 16             // 4096 / (64 lanes * 4 floats)
#define DEPTH 3               // prefetch depth-2 => 3 register buffer sets

typedef float f4 __attribute__((ext_vector_type(4)));

// --- tiny setup kernel: W[4160][8] -> Wt[8][4160] in d_ws ---
__global__ __launch_bounds__(256)
void transpose_w(const float* __restrict__ W, float* __restrict__ Wt) {
    const int k = blockIdx.x * 256 + threadIdx.x;
    if (k < WROWS) {
        float v[NE];
#pragma unroll
        for (int e = 0; e < NE; ++e) v[e] = W[(size_t)k * NE + e];
#pragma unroll
        for (int e = 0; e < NE; ++e) Wt[(size_t)e * WROWS + k] = v[e];
    }
}

// One wave per block, 4 tokens per wave, FULL K per wave.
// R4 structure + CHUNK PHASE STAGGER: block bid walks chunks in order
// (c + 5*bid) mod 16, so concurrent waves spread across the whole 16KB
// row period instead of hammering the same HBM-channel phase in lockstep.
__global__ __launch_bounds__(64, 2)
void topk_gate(const float* __restrict__ x,
               const float* __restrict__ prompt,
               const float* __restrict__ Wt,
               const float* __restrict__ b,
               float* __restrict__ out,
               int tokens)
{
    const int lane  = threadIdx.x;      // 0..63
    const int tbase = blockIdx.x * 4;
    const int klane = lane * 4;
    const int phase = (blockIdx.x * 5) & 15;

    float acc[4][NE];
#pragma unroll
    for (int t = 0; t < 4; ++t)
#pragma unroll
        for (int e = 0; e < NE; ++e) acc[t][e] = 0.f;

    f4 xb[DEPTH][4];
    f4 wb[DEPTH][NE];

    auto load_chunk = [&](int c, int s) {
        const int k = ((c + phase) & 15) * 256 + klane;   // staggered phase
#pragma unroll
        for (int t = 0; t < 4; ++t)
            xb[s][t] = __builtin_nontemporal_load(
                (const f4*)(x + (size_t)(tbase + t) * KDIM + k));
#pragma unroll
        for (int e = 0; e < NE; ++e)
            wb[s][e] = *(const f4*)(Wt + (size_t)e * WROWS + k);
    };

    load_chunk(0, 0);
    load_chunk(1, 1);

#pragma unroll
    for (int c = 0; c < NCHUNK; ++c) {
        if (c + 2 < NCHUNK) load_chunk(c + 2, (c + 2) % DEPTH);
        const int s = c % DEPTH;
#pragma unroll
        for (int t = 0; t < 4; ++t)
#pragma unroll
            for (int e = 0; e < NE; ++e) {
                acc[t][e] = fmaf(xb[s][t].x, wb[s][e].x, acc[t][e]);
                acc[t][e] = fmaf(xb[s][t].y, wb[s][e].y, acc[t][e]);
                acc[t][e] = fmaf(xb[s][t].z, wb[s][e].z, acc[t][e]);
                acc[t][e] = fmaf(xb[s][t].w, wb[s][e].w, acc[t][e]);
            }
    }

    // prompt part (64 dims): lanes 0..15, contiguous Wt rows 4096..4159
    if (lane < 16) {
        const int k = lane * 4;
        f4 pv[4];
#pragma unroll
        for (int t = 0; t < 4; ++t)
            pv[t] = *(const f4*)(prompt + (size_t)(tbase + t) * PDIM + k);
        f4 wv[NE];
#pragma unroll
        for (int e = 0; e < NE; ++e)
            wv[e] = *(const f4*)(Wt + (size_t)e * WROWS + KDIM + k);
#pragma unroll
        for (int t = 0; t < 4; ++t)
#pragma unroll
            for (int e = 0; e < NE; ++e) {
                acc[t][e] = fmaf(pv[t].x, wv[e].x, acc[t][e]);
                acc[t][e] = fmaf(pv[t].y, wv[e].y, acc[t][e]);
                acc[t][e] = fmaf(pv[t].z, wv[e].z, acc[t][e]);
                acc[t][e] = fmaf(pv[t].w, wv[e].w, acc[t][e]);
            }
    }

    // butterfly reduce: every lane ends with full logits for all 4 tokens
#pragma unroll
    for (int t = 0; t < 4; ++t)
#pragma unroll
        for (int e = 0; e < NE; ++e) {
            float v = acc[t][e];
#pragma unroll
            for (int off = 32; off >= 1; off >>= 1)
                v += __shfl_xor(v, off, 64);
            acc[t][e] = v;
        }

    // ---- epilogue: lane = tt*16 + kk*8 + ee -> one mask element per lane ----
    const int tt = lane >> 4;
    const int kk = (lane >> 3) & 1;
    const int ee = lane & 7;

    float lg[NE];
#pragma unroll
    for (int e = 0; e < NE; ++e) {
        float v = acc[0][e];
        if (tt == 1) v = acc[1][e];
        if (tt == 2) v = acc[2][e];
        if (tt == 3) v = acc[3][e];
        lg[e] = v + b[e];
    }

    // top-2, strict > so smallest index wins ties (jax.lax.top_k semantics)
    float v0 = lg[0]; int i0 = 0;
#pragma unroll
    for (int e = 1; e < NE; ++e)
        if (lg[e] > v0) { v0 = lg[e]; i0 = e; }
    float v1 = (i0 == 0) ? lg[1] : lg[0];
    int   i1 = (i0 == 0) ? 1 : 0;
#pragma unroll
    for (int e = 0; e < NE; ++e)
        if (e != i0 && lg[e] > v1) { v1 = lg[e]; i1 = e; }

    float s = 0.f;
#pragma unroll
    for (int e = 0; e < NE; ++e) s += __expf(lg[e] - v0);
    const float g0 = 1.0f / s;
    const float g1 = __expf(v1 - v0) / s;
    const float denom = fmaxf(g0 + g1, EPS_F32);

    const int sel = kk ? i1 : i0;
    const int t_global = tbase + tt;
    out[(size_t)t_global * 16 + kk * 8 + ee] = (ee == sel) ? 1.0f : 0.0f;

    if ((lane & 15) < 2) {
        const float g = (ee == 0) ? (g0 / denom) : (g1 / denom);
        out[(size_t)tokens * 16 + (size_t)t_global * 2 + ee] = g;
    }
}

extern "C" void kernel_launch(void* const* d_in, const int* in_sizes, int n_in,
                              void* d_out, int out_size, void* d_ws, size_t ws_size,
                              hipStream_t stream) {
    const float* x      = (const float*)d_in[0];
    const float* prompt = (const float*)d_in[1];
    const float* W      = (const float*)d_in[2];
    const float* b      = (const float*)d_in[3];
    float* out          = (float*)d_out;
    float* Wt           = (float*)d_ws;          // 8*4160*4 = 133 KB

    const int tokens = in_sizes[0] / KDIM;       // 8192

    hipLaunchKernelGGL(transpose_w, dim3((WROWS + 255) / 256), dim3(256), 0, stream,
                       W, Wt);
    hipLaunchKernelGGL(topk_gate, dim3(tokens / 4), dim3(64), 0, stream,
                       x, prompt, Wt, b, out, tokens);
}